// Round 1
// baseline (289.823 us; speedup 1.0000x reference)
//
#include <hip/hip_runtime.h>
#include <hip/hip_bf16.h>
#include <math.h>

#define B_ 32
#define E_ 16384
#define N_ 1000
#define D_ 128
#define NN_ (N_ * N_)

typedef __attribute__((ext_vector_type(8))) short bf16x8;
typedef __attribute__((ext_vector_type(4))) float f32x4;
typedef __attribute__((ext_vector_type(4))) short short4v;

// fp32 -> bf16, round-to-nearest-even (finite inputs only)
__device__ __forceinline__ unsigned short f2bf(float f) {
    unsigned u = __float_as_uint(f);
    u += 0x7FFFu + ((u >> 16) & 1u);
    return (unsigned short)(u >> 16);
}

// XOR-swizzle byte address within a [row][128] bf16 LDS tile (256 B rows).
// Spreads the 16-rows-same-column ds_read_b128 pattern across banks (G4).
__device__ __forceinline__ unsigned swzb(unsigned row, unsigned byteInRow) {
    return row * 256u + (byteInRow ^ ((row & 7u) << 4));
}

__device__ __forceinline__ f32x4 mfma16(bf16x8 a, bf16x8 b, f32x4 c) {
    return __builtin_amdgcn_mfma_f32_16x16x32_bf16(a, b, c, 0, 0, 0);
}

// decode packed cell: 0 = empty, else low 18 bits = quantized val+1 over [0,10]
__device__ __forceinline__ float decq(unsigned x) {
    return x ? (float)((x & 0x3FFFFu) - 1u) * (10.0f / 262142.0f) : 0.0f;
}

__global__ __launch_bounds__(256, 2) void mlp_scatter_kernel(
    const float* __restrict__ X, const int* __restrict__ EI,
    const float* __restrict__ W1, const float* __restrict__ b1,
    const float* __restrict__ W2, const float* __restrict__ b2,
    const float* __restrict__ Wo, const float* __restrict__ bo,
    unsigned* __restrict__ out)
{
    __shared__ __align__(16) short WbS[D_ * D_];  // 32 KB: W1 then W2 (bf16, swizzled)
    __shared__ __align__(16) short HbS[D_ * D_];  // 32 KB: h1 tile (bf16, swizzled)
    char* wb = (char*)WbS;
    char* hb = (char*)HbS;

    const int tid = threadIdx.x;
    const int lane = tid & 63;
    const int wv = tid >> 6;        // wave 0..3, owns 32 edges
    const int l15 = lane & 15;
    const int g = lane >> 4;        // 0..3
    const long ebase = (long)blockIdx.x * 128;   // 128 edges per block, tile within one batch

    auto stageW = [&](const float* __restrict__ Wsrc) {
        // 128x128 fp32 row-major -> bf16 swizzled LDS, coalesced float4 loads
        for (int it = 0; it < 16; ++it) {
            int idx4 = tid + it * 256;
            int elem = idx4 << 2;
            int row = elem >> 7, col = elem & 127;
            float4 v = ((const float4*)Wsrc)[idx4];
            short4v s;
            s[0] = (short)f2bf(v.x); s[1] = (short)f2bf(v.y);
            s[2] = (short)f2bf(v.z); s[3] = (short)f2bf(v.w);
            *(short4v*)(wb + swzb(row, col * 2)) = s;
        }
    };

    // ---- stage W1 ----
    stageW(W1);
    __syncthreads();

    // ---- GEMM1: z1 = X @ W1^T  (M=edges, N=feat, K=d) ----
    f32x4 acc[2][8];
    #pragma unroll
    for (int m = 0; m < 2; ++m)
        #pragma unroll
        for (int n = 0; n < 8; ++n)
            acc[m][n] = (f32x4){0.f, 0.f, 0.f, 0.f};

    #pragma unroll
    for (int ks = 0; ks < 4; ++ks) {
        bf16x8 a[2];
        #pragma unroll
        for (int m = 0; m < 2; ++m) {
            // A-frag: lane row = l15 (edge), k = g*8 + j, contiguous fp32 from global
            const float* p = X + (ebase + wv * 32 + m * 16 + l15) * D_ + ks * 32 + g * 8;
            float4 u0 = *(const float4*)p;
            float4 u1 = *(const float4*)(p + 4);
            bf16x8 t;
            t[0] = (short)f2bf(u0.x); t[1] = (short)f2bf(u0.y);
            t[2] = (short)f2bf(u0.z); t[3] = (short)f2bf(u0.w);
            t[4] = (short)f2bf(u1.x); t[5] = (short)f2bf(u1.y);
            t[6] = (short)f2bf(u1.z); t[7] = (short)f2bf(u1.w);
            a[m] = t;
        }
        #pragma unroll
        for (int n = 0; n < 8; ++n) {
            // B-frag: lane col = l15 (out-feat), k contiguous -> row (l15+16n) of W
            bf16x8 bf = *(bf16x8*)(wb + swzb(l15 + n * 16, ks * 64 + g * 16));
            acc[0][n] = mfma16(a[0], bf, acc[0][n]);
            acc[1][n] = mfma16(a[1], bf, acc[1][n]);
        }
    }

    // ---- bias + silu, write h1 tile to LDS (C layout: row=(g*4+r), col=l15+16n) ----
    #pragma unroll
    for (int n = 0; n < 8; ++n) {
        float bias = b1[l15 + n * 16];
        #pragma unroll
        for (int m = 0; m < 2; ++m) {
            #pragma unroll
            for (int r = 0; r < 4; ++r) {
                float z = acc[m][n][r] + bias;
                float h = z / (1.0f + __expf(-z));
                int row = wv * 32 + m * 16 + g * 4 + r;
                *(short*)(hb + swzb(row, (l15 + n * 16) * 2)) = (short)f2bf(h);
            }
        }
    }
    __syncthreads();

    // ---- stage W2 (reuse Wb) ----
    stageW(W2);
    __syncthreads();

    // ---- GEMM2: z2 = h1 @ W2^T ----
    f32x4 acc2[2][8];
    #pragma unroll
    for (int m = 0; m < 2; ++m)
        #pragma unroll
        for (int n = 0; n < 8; ++n)
            acc2[m][n] = (f32x4){0.f, 0.f, 0.f, 0.f};

    #pragma unroll
    for (int ks = 0; ks < 4; ++ks) {
        bf16x8 a[2];
        #pragma unroll
        for (int m = 0; m < 2; ++m)
            a[m] = *(bf16x8*)(hb + swzb(wv * 32 + m * 16 + l15, ks * 64 + g * 16));
        #pragma unroll
        for (int n = 0; n < 8; ++n) {
            bf16x8 bf = *(bf16x8*)(wb + swzb(l15 + n * 16, ks * 64 + g * 16));
            acc2[0][n] = mfma16(a[0], bf, acc2[0][n]);
            acc2[1][n] = mfma16(a[1], bf, acc2[1][n]);
        }
    }

    // ---- bias + silu + dot(Wo) in-register, reduce across the 16-lane group ----
    float zed[2][4] = {{0.f, 0.f, 0.f, 0.f}, {0.f, 0.f, 0.f, 0.f}};
    #pragma unroll
    for (int n = 0; n < 8; ++n) {
        float bias = b2[l15 + n * 16];
        float wo = Wo[l15 + n * 16];
        #pragma unroll
        for (int m = 0; m < 2; ++m) {
            #pragma unroll
            for (int r = 0; r < 4; ++r) {
                float z = acc2[m][n][r] + bias;
                float h = z / (1.0f + __expf(-z));
                zed[m][r] += h * wo;
            }
        }
    }
    #pragma unroll
    for (int mask = 1; mask < 16; mask <<= 1) {
        #pragma unroll
        for (int m = 0; m < 2; ++m)
            #pragma unroll
            for (int r = 0; r < 4; ++r)
                zed[m][r] += __shfl_xor(zed[m][r], mask, 64);
    }

    // ---- sigmoid*10, pack (e<<18 | q), atomicMax scatter (last-e-wins) ----
    if (l15 == 0) {
        float bo0 = bo[0];
        #pragma unroll
        for (int m = 0; m < 2; ++m) {
            #pragma unroll
            for (int r = 0; r < 4; ++r) {
                long ge = ebase + wv * 32 + m * 16 + g * 4 + r;
                int b = (int)(ge >> 14);          // / E_
                int eb = (int)(ge & 16383);       // % E_ (14 bits)
                int s = EI[(size_t)b * 2 * E_ + eb];
                int d = EI[(size_t)b * 2 * E_ + E_ + eb];
                float z = zed[m][r] + bo0;
                float val = 10.0f / (1.0f + __expf(-z));
                unsigned q = (unsigned)(val * 26214.2f + 0.5f) + 1u;  // 262142/10
                if (q > 0x3FFFFu) q = 0x3FFFFu;
                unsigned packed = ((unsigned)eb << 18) | q;
                atomicMax(out + ((size_t)b * NN_ + (size_t)s * N_ + d), packed);
            }
        }
    }
}

// In-place decode + symmetrize. Each block owns the unordered tile pair
// (ti,tj)/(tj,ti) of one batch; stages both 32x32 tiles in LDS so transpose
// reads are conflict-free and all reads complete before any write.
__global__ __launch_bounds__(256) void symmetrize_kernel(unsigned* __restrict__ out) {
    const int b = blockIdx.y;
    const int ti = blockIdx.x >> 5;
    const int tj = blockIdx.x & 31;
    if (ti > tj) return;
    __shared__ unsigned ta[32][33];
    __shared__ unsigned tb[32][33];
    const int j = threadIdx.x & 31;
    const int i0 = threadIdx.x >> 5;
    unsigned* ob = out + (size_t)b * NN_;
    float* of = (float*)ob;
    #pragma unroll
    for (int rr = 0; rr < 4; ++rr) {
        int i = rr * 8 + i0;
        int gi = ti * 32 + i, gj = tj * 32 + j;
        ta[i][j] = (gi < N_ && gj < N_) ? ob[(size_t)gi * N_ + gj] : 0u;
        int hi = tj * 32 + i, hj = ti * 32 + j;
        tb[i][j] = (hi < N_ && hj < N_) ? ob[(size_t)hi * N_ + hj] : 0u;
    }
    __syncthreads();
    #pragma unroll
    for (int rr = 0; rr < 4; ++rr) {
        int i = rr * 8 + i0;
        int gi = ti * 32 + i, gj = tj * 32 + j;
        if (gi < N_ && gj < N_)
            of[(size_t)gi * N_ + gj] = 0.5f * (decq(ta[i][j]) + decq(tb[j][i]));
        int hi = tj * 32 + i, hj = ti * 32 + j;
        if (hi < N_ && hj < N_)
            of[(size_t)hi * N_ + hj] = 0.5f * (decq(tb[i][j]) + decq(ta[j][i]));
    }
}

extern "C" void kernel_launch(void* const* d_in, const int* in_sizes, int n_in,
                              void* d_out, int out_size, void* d_ws, size_t ws_size,
                              hipStream_t stream) {
    const float* X  = (const float*)d_in[0];
    const int*   EI = (const int*)d_in[1];
    const float* W1 = (const float*)d_in[2];
    const float* b1 = (const float*)d_in[3];
    const float* W2 = (const float*)d_in[4];
    const float* b2 = (const float*)d_in[5];
    const float* Wo = (const float*)d_in[6];
    const float* bo = (const float*)d_in[7];
    unsigned* out = (unsigned*)d_out;

    hipMemsetAsync(d_out, 0, (size_t)B_ * NN_ * sizeof(float), stream);
    mlp_scatter_kernel<<<dim3((B_ * E_) / 128), dim3(256), 0, stream>>>(
        X, EI, W1, b1, W2, b2, Wo, bo, out);
    symmetrize_kernel<<<dim3(32 * 32, B_), dim3(256), 0, stream>>>(out);
}

// Round 2
// 256.195 us; speedup vs baseline: 1.1313x; 1.1313x over previous
//
#include <hip/hip_runtime.h>
#include <math.h>

#define B_ 32
#define E_ 16384
#define N_ 1000
#define D_ 128
#define NN_ (N_ * N_)

typedef __attribute__((ext_vector_type(8))) short bf16x8;
typedef __attribute__((ext_vector_type(4))) float f32x4;

// fp32 -> bf16, round-to-nearest-even (finite inputs only)
__device__ __forceinline__ unsigned short f2bf(float f) {
    unsigned u = __float_as_uint(f);
    u += 0x7FFFu + ((u >> 16) & 1u);
    return (unsigned short)(u >> 16);
}

__device__ __forceinline__ f32x4 mfma16(bf16x8 a, bf16x8 b, f32x4 c) {
    return __builtin_amdgcn_mfma_f32_16x16x32_bf16(a, b, c, 0, 0, 0);
}

__device__ __forceinline__ float silu_(float z) {
    return z / (1.0f + __expf(-z));
}

// decode packed cell: 0 = empty, else low 18 bits = quantized val+1 over [0,10]
__device__ __forceinline__ float decq(unsigned x) {
    return x ? (float)((x & 0x3FFFFu) - 1u) * (10.0f / 262142.0f) : 0.0f;
}

// async global->LDS, 16B per lane (dest = wave-uniform base + lane*16)
__device__ __forceinline__ void gload_lds16(const void* g, void* l) {
    __builtin_amdgcn_global_load_lds(
        (const __attribute__((address_space(1))) unsigned*)g,
        (__attribute__((address_space(3))) unsigned*)l, 16, 0, 0);
}

// Pre-swizzle W1,W2 (128x128 fp32) -> bf16 at byte  row*256 + ((col*2)^((row&7)<<4))
// so a LINEAR global_load_lds reproduces the swizzled LDS image (rule 21:
// linear dest + inverse-swizzled source).
__global__ void prep_weights(const float* __restrict__ W1,
                             const float* __restrict__ W2,
                             unsigned short* __restrict__ wsz) {
    int t = blockIdx.x * 256 + threadIdx.x;   // 0..32767
    int w = t >> 14, e = t & 16383;
    int row = e >> 7, col = e & 127;
    float v = (w ? W2 : W1)[e];
    char* dst = (char*)wsz + (size_t)w * 32768 + row * 256 + ((col * 2) ^ ((row & 7) << 4));
    *(unsigned short*)dst = f2bf(v);
}

__global__ __launch_bounds__(256, 2) void mlp_scatter_kernel(
    const float* __restrict__ X, const int* __restrict__ EI,
    const unsigned short* __restrict__ wsz,
    const float* __restrict__ b1, const float* __restrict__ b2,
    const float* __restrict__ Wo, const float* __restrict__ bo,
    unsigned* __restrict__ out)
{
    __shared__ __align__(16) char Wb[65536];  // W1(32KB) | W2(32KB), bf16 swizzled
    __shared__ __align__(16) char Hs[16384];  // 4 waves x (32 edges x 64 feats) bf16

    const int tid = threadIdx.x;
    const int lane = tid & 63;
    const int wv = tid >> 6;
    const int l15 = lane & 15;
    const int g = lane >> 4;

    const int bb = blockIdx.x >> 7;            // batch
    const int e0 = (blockIdx.x & 127) * 128;   // edge base within batch
    const float* Xb = X + ((size_t)bb * E_ + e0) * D_;

    // small preloads (L2-resident) — issue first
    float b1v[8], b2v[8], wov[8];
    #pragma unroll
    for (int n = 0; n < 8; ++n) {
        b1v[n] = b1[l15 + 16 * n];
        b2v[n] = b2[l15 + 16 * n];
        wov[n] = Wo[l15 + 16 * n];
    }
    float bo0 = bo[0];

    // A loads (fp32 X) issued BEFORE staging so HBM latency overlaps it
    float4 af[2][4][2];
    #pragma unroll
    for (int m = 0; m < 2; ++m)
        #pragma unroll
        for (int ks = 0; ks < 4; ++ks) {
            const float* p = Xb + (size_t)(wv * 32 + m * 16 + l15) * D_ + ks * 32 + g * 8;
            af[m][ks][0] = *(const float4*)p;
            af[m][ks][1] = *(const float4*)(p + 4);
        }

    // stage both weight matrices: 64KB linear, zero VALU
    #pragma unroll
    for (int it = 0; it < 16; ++it) {
        int off = it * 4096 + tid * 16;
        gload_lds16((const char*)wsz + off, Wb + off);
    }
    __syncthreads();   // the ONLY barrier

    // convert A to bf16 fragments
    bf16x8 a[2][4];
    #pragma unroll
    for (int m = 0; m < 2; ++m)
        #pragma unroll
        for (int ks = 0; ks < 4; ++ks) {
            bf16x8 t;
            #pragma unroll
            for (int j = 0; j < 4; ++j) {
                t[j]     = (short)f2bf(((const float*)&af[m][ks][0])[j]);
                t[j + 4] = (short)f2bf(((const float*)&af[m][ks][1])[j]);
            }
            a[m][ks] = t;
        }

    char* hw = Hs + wv * 4096;   // wave-private h tile: no cross-wave sync needed

    f32x4 acc2[2][8];
    #pragma unroll
    for (int m = 0; m < 2; ++m)
        #pragma unroll
        for (int n = 0; n < 8; ++n)
            acc2[m][n] = (f32x4){0.f, 0.f, 0.f, 0.f};

    #pragma unroll
    for (int half = 0; half < 2; ++half) {
        // ---- GEMM1, output-feature half: n = half*4 .. half*4+3 ----
        f32x4 acc1[2][4];
        #pragma unroll
        for (int m = 0; m < 2; ++m)
            #pragma unroll
            for (int nn = 0; nn < 4; ++nn)
                acc1[m][nn] = (f32x4){0.f, 0.f, 0.f, 0.f};

        #pragma unroll
        for (int ks = 0; ks < 4; ++ks) {
            #pragma unroll
            for (int nn = 0; nn < 4; ++nn) {
                int row = l15 + (half * 4 + nn) * 16;
                bf16x8 bw = *(const bf16x8*)(Wb + row * 256 + ((ks * 64 + g * 16) ^ ((row & 7) << 4)));
                acc1[0][nn] = mfma16(a[0][ks], bw, acc1[0][nn]);
                acc1[1][nn] = mfma16(a[1][ks], bw, acc1[1][nn]);
            }
        }

        // ---- bias+silu -> wave-private H half-tile (rows=edges, cols=64 feats) ----
        #pragma unroll
        for (int nn = 0; nn < 4; ++nn) {
            float bias = b1v[half * 4 + nn];
            #pragma unroll
            for (int m = 0; m < 2; ++m)
                #pragma unroll
                for (int r = 0; r < 4; ++r) {
                    float h = silu_(acc1[m][nn][r] + bias);
                    int row = m * 16 + g * 4 + r;
                    *(short*)(hw + row * 128 + (((l15 + 16 * nn) * 2) ^ ((row & 7) << 4))) = (short)f2bf(h);
                }
        }

        // ---- GEMM2 partial: k = half*64 .. half*64+63 (same-wave LDS RAW: in-order) ----
        #pragma unroll
        for (int p2 = 0; p2 < 2; ++p2) {
            bf16x8 a2[2];
            #pragma unroll
            for (int m = 0; m < 2; ++m) {
                int row = m * 16 + l15;
                a2[m] = *(const bf16x8*)(hw + row * 128 + ((p2 * 64 + g * 16) ^ ((row & 7) << 4)));
            }
            #pragma unroll
            for (int n = 0; n < 8; ++n) {
                int row = l15 + 16 * n;
                bf16x8 bw = *(const bf16x8*)(Wb + 32768 + row * 256 +
                              (((half * 2 + p2) * 64 + g * 16) ^ ((row & 7) << 4)));
                acc2[0][n] = mfma16(a2[0], bw, acc2[0][n]);
                acc2[1][n] = mfma16(a2[1], bw, acc2[1][n]);
            }
        }
    }

    // ---- bias + silu + dot(Wo) in-register, reduce across 16-lane group ----
    float zed[2][4] = {{0.f, 0.f, 0.f, 0.f}, {0.f, 0.f, 0.f, 0.f}};
    #pragma unroll
    for (int n = 0; n < 8; ++n) {
        #pragma unroll
        for (int m = 0; m < 2; ++m)
            #pragma unroll
            for (int r = 0; r < 4; ++r) {
                float h = silu_(acc2[m][n][r] + b2v[n]);
                zed[m][r] += h * wov[n];
            }
    }
    #pragma unroll
    for (int mask = 1; mask < 16; mask <<= 1) {
        #pragma unroll
        for (int m = 0; m < 2; ++m)
            #pragma unroll
            for (int r = 0; r < 4; ++r)
                zed[m][r] += __shfl_xor(zed[m][r], mask, 64);
    }

    // ---- sigmoid*10, pack (e<<18 | q), atomicMax scatter (last-e-wins) ----
    if (l15 == 0) {
        #pragma unroll
        for (int m = 0; m < 2; ++m) {
            #pragma unroll
            for (int r = 0; r < 4; ++r) {
                int eb = e0 + wv * 32 + m * 16 + g * 4 + r;   // 0..16383
                int s = EI[(size_t)bb * 2 * E_ + eb];
                int d = EI[(size_t)bb * 2 * E_ + E_ + eb];
                float z = zed[m][r] + bo0;
                float val = 10.0f / (1.0f + __expf(-z));
                unsigned q = (unsigned)(val * 26214.2f + 0.5f) + 1u;  // 262142/10
                if (q > 0x3FFFFu) q = 0x3FFFFu;
                unsigned packed = ((unsigned)eb << 18) | q;
                atomicMax(out + ((size_t)bb * NN_ + (size_t)s * N_ + d), packed);
            }
        }
    }
}

// In-place decode + symmetrize. Each block owns the unordered tile pair
// (ti,tj)/(tj,ti) of one batch; stages both 32x32 tiles in LDS so transpose
// reads are conflict-free and all reads complete before any write.
__global__ __launch_bounds__(256) void symmetrize_kernel(unsigned* __restrict__ out) {
    const int b = blockIdx.y;
    const int ti = blockIdx.x >> 5;
    const int tj = blockIdx.x & 31;
    if (ti > tj) return;
    __shared__ unsigned ta[32][33];
    __shared__ unsigned tb[32][33];
    const int j = threadIdx.x & 31;
    const int i0 = threadIdx.x >> 5;
    unsigned* ob = out + (size_t)b * NN_;
    float* of = (float*)ob;
    #pragma unroll
    for (int rr = 0; rr < 4; ++rr) {
        int i = rr * 8 + i0;
        int gi = ti * 32 + i, gj = tj * 32 + j;
        ta[i][j] = (gi < N_ && gj < N_) ? ob[(size_t)gi * N_ + gj] : 0u;
        int hi = tj * 32 + i, hj = ti * 32 + j;
        tb[i][j] = (hi < N_ && hj < N_) ? ob[(size_t)hi * N_ + hj] : 0u;
    }
    __syncthreads();
    #pragma unroll
    for (int rr = 0; rr < 4; ++rr) {
        int i = rr * 8 + i0;
        int gi = ti * 32 + i, gj = tj * 32 + j;
        if (gi < N_ && gj < N_)
            of[(size_t)gi * N_ + gj] = 0.5f * (decq(ta[i][j]) + decq(tb[j][i]));
        int hi = tj * 32 + i, hj = ti * 32 + j;
        if (hi < N_ && hj < N_)
            of[(size_t)hi * N_ + hj] = 0.5f * (decq(tb[i][j]) + decq(ta[j][i]));
    }
}

extern "C" void kernel_launch(void* const* d_in, const int* in_sizes, int n_in,
                              void* d_out, int out_size, void* d_ws, size_t ws_size,
                              hipStream_t stream) {
    const float* X  = (const float*)d_in[0];
    const int*   EI = (const int*)d_in[1];
    const float* W1 = (const float*)d_in[2];
    const float* b1 = (const float*)d_in[3];
    const float* W2 = (const float*)d_in[4];
    const float* b2 = (const float*)d_in[5];
    const float* Wo = (const float*)d_in[6];
    const float* bo = (const float*)d_in[7];
    unsigned* out = (unsigned*)d_out;
    unsigned short* wsz = (unsigned short*)d_ws;

    prep_weights<<<dim3(128), dim3(256), 0, stream>>>(W1, W2, wsz);
    hipMemsetAsync(d_out, 0, (size_t)B_ * NN_ * sizeof(float), stream);
    mlp_scatter_kernel<<<dim3((B_ * E_) / 128), dim3(256), 0, stream>>>(
        X, EI, wsz, b1, b2, Wo, bo, out);
    symmetrize_kernel<<<dim3(32 * 32, B_), dim3(256), 0, stream>>>(out);
}